// Round 2
// baseline (91.407 us; speedup 1.0000x reference)
//
#include <hip/hip_runtime.h>
#include <math.h>

#define NB 2048
#define ND 784
#define NK 128
#define BM 8            // rows per block
#define DSPLIT 7        // D chunks
#define DPB (ND / DSPLIT)   // 112, multiple of 4
#define KD (ND * NK)        // 100352

// ws layout (floats):
//   ta[KD] | tb[KD] | tc[KD] | logw[NK] | part[DSPLIT*NB*NK]
// total = 3*100352 + 128 + 7*2048*128 = 2.14M floats ≈ 8.4 MB

__global__ __launch_bounds__(256) void k_tables(
    const float* __restrict__ w, const float* __restrict__ mu,
    const float* __restrict__ cov, float* __restrict__ ws) {
  int idx = blockIdx.x * 256 + threadIdx.x;
  float* ta = ws;
  float* tb = ws + KD;
  float* tc = ws + 2 * KD;
  float* lw = ws + 3 * KD;
  if (idx < KD) {
    int k = idx & (NK - 1);   // table layout [d][k]
    int d = idx >> 7;
    float c = cov[k * ND + d];
    float m = mu[k * ND + d];
    float inv2 = 0.5f / c;
    ta[idx] = -inv2;
    tb[idx] = m / c;
    tc[idx] = -m * m * inv2 - 0.5f * logf(c);
  }
  if (idx < NK) lw[idx] = logf(w[idx]);
}

// Grid: (NB/BM) * DSPLIT = 256*7 = 1792 blocks = 7 blocks/CU -> 28 waves/CU.
// Block: 256 threads. tx = tid&31 -> k-quad (4k), ty = tid>>5 -> row (0..7).
// Each thread: 1 row x 4 centers x 112 dims.
__global__ __launch_bounds__(256) void k_main(
    const float* __restrict__ data, const float* __restrict__ mask,
    float* __restrict__ ws) {
  const float* ta = ws;
  const float* tb = ws + KD;
  const float* tc = ws + 2 * KD;
  float* part = ws + 3 * KD + NK;

  int blk = blockIdx.x;
  int mt  = blk / DSPLIT;
  int dsp = blk % DSPLIT;
  int r   = mt * BM + (threadIdx.x >> 5);
  int d0  = dsp * DPB;
  int kb  = (threadIdx.x & 31) << 2;

  float acc0 = 0.f, acc1 = 0.f, acc2 = 0.f, acc3 = 0.f;

  const float* drow = data + (size_t)r * ND;
  const float* mrow = mask + (size_t)r * ND;

  for (int dg = 0; dg < DPB; dg += 4) {
    int d = d0 + dg;
    float4 x = *(const float4*)(drow + d);
    float4 m = *(const float4*)(mrow + d);
    float xs[4] = {x.x, x.y, x.z, x.w};
    float ms[4] = {m.x, m.y, m.z, m.w};
#pragma unroll
    for (int dd = 0; dd < 4; dd++) {
      float4 a = *(const float4*)(ta + (size_t)(d + dd) * NK + kb);
      float4 b = *(const float4*)(tb + (size_t)(d + dd) * NK + kb);
      float4 c = *(const float4*)(tc + (size_t)(d + dd) * NK + kb);
      float m0 = ms[dd];
      float m1 = m0 * xs[dd];
      float m2 = m1 * xs[dd];
      acc0 = fmaf(m2, a.x, fmaf(m1, b.x, fmaf(m0, c.x, acc0)));
      acc1 = fmaf(m2, a.y, fmaf(m1, b.y, fmaf(m0, c.y, acc1)));
      acc2 = fmaf(m2, a.z, fmaf(m1, b.z, fmaf(m0, c.z, acc2)));
      acc3 = fmaf(m2, a.w, fmaf(m1, b.w, fmaf(m0, c.w, acc3)));
    }
  }

  float4 v = make_float4(acc0, acc1, acc2, acc3);
  *(float4*)(part + ((size_t)dsp * NB + r) * NK + kb) = v;
}

// One wave per batch row: reduce DSPLIT partials, +log w, NaN fix,
// log-sum-exp with the reference's per-term +1e-8, exp.
__global__ __launch_bounds__(256) void k_final(
    const float* __restrict__ ws, float* __restrict__ out) {
  const float* lw   = ws + 3 * KD;
  const float* part = ws + 3 * KD + NK;
  int lane = threadIdx.x & 63;
  int wv   = threadIdx.x >> 6;
  int b = blockIdx.x * 4 + wv;

  float dep[2];
#pragma unroll
  for (int t = 0; t < 2; t++) {
    int k = lane + t * 64;
    float s = 0.f;
#pragma unroll
    for (int sp = 0; sp < DSPLIT; sp++)
      s += part[((size_t)sp * NB + b) * NK + k];
    s += lw[k];
    if (isnan(s)) s = 0.f;
    dep[t] = s;
  }
  float mx = fmaxf(dep[0], dep[1]);
#pragma unroll
  for (int off = 32; off; off >>= 1) mx = fmaxf(mx, __shfl_xor(mx, off));
  // reference: sum_k (exp(dep-max) + 1e-8)  -> 2 terms per lane
  float sum = expf(dep[0] - mx) + expf(dep[1] - mx) + 2e-8f;
#pragma unroll
  for (int off = 32; off; off >>= 1) sum += __shfl_xor(sum, off);
  float lse = logf(sum) + mx;
  out[(size_t)b * NK + lane]      = expf(dep[0] - lse);
  out[(size_t)b * NK + lane + 64] = expf(dep[1] - lse);
}

extern "C" void kernel_launch(void* const* d_in, const int* in_sizes, int n_in,
                              void* d_out, int out_size, void* d_ws, size_t ws_size,
                              hipStream_t stream) {
  const float* data = (const float*)d_in[0];
  const float* mask = (const float*)d_in[1];
  const float* wts  = (const float*)d_in[2];
  const float* mu   = (const float*)d_in[3];
  const float* cov  = (const float*)d_in[4];
  float* ws  = (float*)d_ws;
  float* out = (float*)d_out;

  k_tables<<<(KD + 255) / 256, 256, 0, stream>>>(wts, mu, cov, ws);
  k_main<<<(NB / BM) * DSPLIT, 256, 0, stream>>>(data, mask, ws);
  k_final<<<NB / 4, 256, 0, stream>>>(ws, out);
}

// Round 3
// 44.044 us; speedup vs baseline: 2.0754x; 2.0754x over previous
//
#include <hip/hip_runtime.h>
#include <math.h>

#define NB 2048
#define ND 784
#define NK 128
#define BM 32               // rows per k_main block (8 ty x 4 rows each)
#define DSPLIT 14           // D chunks -> partials
#define DPB (ND / DSPLIT)   // 56 dims per block
#define DSTG 28             // dims per LDS stage (2 stages per block)
#define KD (ND * NK)        // 100352
#define TBL (ND * 3 * NK)   // interleaved table floats = 301056

// ws layout (floats):
//   T[TBL]  : interleaved tables, per dim d: [ta[128] | tb[128] | tc[128]]
//   lw[NK]
//   part[DSPLIT*NB*NK]
// total = 301056 + 128 + 14*2048*128 = 3,971,200 floats ~= 15.9 MB

__global__ __launch_bounds__(256) void k_tables(
    const float* __restrict__ w, const float* __restrict__ mu,
    const float* __restrict__ cov, float* __restrict__ ws) {
  int idx = blockIdx.x * 256 + threadIdx.x;   // grid covers KD exactly
  float* T  = ws;
  float* lw = ws + TBL;
  int d = idx >> 7;
  int k = idx & (NK - 1);
  float c = cov[k * ND + d];
  float m = mu[k * ND + d];
  float inv2 = 0.5f / c;
  T[d * 384 + k]       = -inv2;                      // ta
  T[d * 384 + 128 + k] = m / c;                      // tb
  T[d * 384 + 256 + k] = -m * m * inv2 - 0.5f * logf(c);  // tc
  if (idx < NK) lw[idx] = logf(w[idx]);
}

// Grid: (NB/BM) * DSPLIT = 64*14 = 896 blocks, 256 threads.
// tx = tid&31 -> k-quad (4 centers), ty = tid>>5 -> 4-row group.
// Tables staged in LDS (2 stages of 28 dims, 43008 B), reused by all 32 rows.
__global__ __launch_bounds__(256) void k_main(
    const float* __restrict__ data, const float* __restrict__ mask,
    const float* __restrict__ ws, float* __restrict__ part) {
  __shared__ float lds[DSTG * 384];   // 10752 floats = 43008 B

  const float* T = ws;
  int mt  = blockIdx.x / DSPLIT;
  int dsp = blockIdx.x % DSPLIT;
  int r0  = mt * BM;
  int d0  = dsp * DPB;
  int tx  = threadIdx.x & 31;
  int ty  = threadIdx.x >> 5;
  int kb  = tx << 2;

  float acc[4][4];
#pragma unroll
  for (int i = 0; i < 4; i++)
#pragma unroll
    for (int j = 0; j < 4; j++) acc[i][j] = 0.f;

  for (int s = 0; s < 2; ++s) {
    int db = d0 + s * DSTG;
    if (s) __syncthreads();           // protect previous stage's reads
    // flat contiguous copy: 28 dims * 384 floats = 2688 float4
    const float4* src = (const float4*)(T + (size_t)db * 384);
    float4* dst = (float4*)lds;
    for (int i = threadIdx.x; i < DSTG * 96; i += 256) dst[i] = src[i];
    __syncthreads();

#pragma unroll 2
    for (int dg = 0; dg < DSTG; dg += 4) {
      float4 a[4], b[4], c[4];
#pragma unroll
      for (int dd = 0; dd < 4; dd++) {
        const float* base = lds + (dg + dd) * 384 + kb;
        a[dd] = *(const float4*)(base);
        b[dd] = *(const float4*)(base + 128);
        c[dd] = *(const float4*)(base + 256);
      }
#pragma unroll
      for (int i = 0; i < 4; i++) {
        int r = r0 + (ty << 2) + i;
        int d = db + dg;
        float4 x = *(const float4*)(data + (size_t)r * ND + d);
        float4 m = *(const float4*)(mask + (size_t)r * ND + d);
        float xs[4] = {x.x, x.y, x.z, x.w};
        float ms[4] = {m.x, m.y, m.z, m.w};
#pragma unroll
        for (int dd = 0; dd < 4; dd++) {
          float m0 = ms[dd];
          float m1 = m0 * xs[dd];
          float m2 = m1 * xs[dd];
          acc[i][0] = fmaf(m2, a[dd].x, fmaf(m1, b[dd].x, fmaf(m0, c[dd].x, acc[i][0])));
          acc[i][1] = fmaf(m2, a[dd].y, fmaf(m1, b[dd].y, fmaf(m0, c[dd].y, acc[i][1])));
          acc[i][2] = fmaf(m2, a[dd].z, fmaf(m1, b[dd].z, fmaf(m0, c[dd].z, acc[i][2])));
          acc[i][3] = fmaf(m2, a[dd].w, fmaf(m1, b[dd].w, fmaf(m0, c[dd].w, acc[i][3])));
        }
      }
    }
  }

#pragma unroll
  for (int i = 0; i < 4; i++) {
    int r = r0 + (ty << 2) + i;
    float4 v = make_float4(acc[i][0], acc[i][1], acc[i][2], acc[i][3]);
    *(float4*)(part + ((size_t)dsp * NB + r) * NK + kb) = v;
  }
}

// One wave per batch row: reduce DSPLIT partials, +log w, NaN fix,
// log-sum-exp with the reference's per-term +1e-8, exp.
__global__ __launch_bounds__(256) void k_final(
    const float* __restrict__ ws, float* __restrict__ out) {
  const float* lw   = ws + TBL;
  const float* part = ws + TBL + NK;
  int lane = threadIdx.x & 63;
  int wv   = threadIdx.x >> 6;
  int b = blockIdx.x * 4 + wv;

  float dep[2];
#pragma unroll
  for (int t = 0; t < 2; t++) {
    int k = lane + t * 64;
    float s = 0.f;
#pragma unroll
    for (int sp = 0; sp < DSPLIT; sp++)
      s += part[((size_t)sp * NB + b) * NK + k];
    s += lw[k];
    if (isnan(s)) s = 0.f;
    dep[t] = s;
  }
  float mx = fmaxf(dep[0], dep[1]);
#pragma unroll
  for (int off = 32; off; off >>= 1) mx = fmaxf(mx, __shfl_xor(mx, off));
  // reference: sum_k (exp(dep-max) + 1e-8) -> 2 terms per lane
  float sum = expf(dep[0] - mx) + expf(dep[1] - mx) + 2e-8f;
#pragma unroll
  for (int off = 32; off; off >>= 1) sum += __shfl_xor(sum, off);
  float lse = logf(sum) + mx;
  out[(size_t)b * NK + lane]      = expf(dep[0] - lse);
  out[(size_t)b * NK + lane + 64] = expf(dep[1] - lse);
}

extern "C" void kernel_launch(void* const* d_in, const int* in_sizes, int n_in,
                              void* d_out, int out_size, void* d_ws, size_t ws_size,
                              hipStream_t stream) {
  const float* data = (const float*)d_in[0];
  const float* mask = (const float*)d_in[1];
  const float* wts  = (const float*)d_in[2];
  const float* mu   = (const float*)d_in[3];
  const float* cov  = (const float*)d_in[4];
  float* ws   = (float*)d_ws;
  float* part = ws + TBL + NK;
  float* out  = (float*)d_out;

  k_tables<<<KD / 256, 256, 0, stream>>>(wts, mu, cov, ws);
  k_main<<<(NB / BM) * DSPLIT, 256, 0, stream>>>(data, mask, ws, part);
  k_final<<<NB / 4, 256, 0, stream>>>(ws, out);
}

// Round 4
// 42.401 us; speedup vs baseline: 2.1558x; 1.0387x over previous
//
#include <hip/hip_runtime.h>
#include <math.h>

#define NB 2048
#define ND 784
#define NK 128
#define BM 64               // rows per k_main block (8 ty x 8 rows each)
#define DSPLIT 28           // D chunks -> partials
#define DPB 28              // dims per block = one LDS stage
#define KD (ND * NK)        // 100352
#define TBL (ND * 3 * NK)   // interleaved table floats = 301056

// ws layout (floats):
//   T[TBL]  : interleaved tables, per dim d: [ta[128] | tb[128] | tc[128]]
//   lw[NK]
//   part[DSPLIT*NB*NK]  = 28 MB region
// total = 301056 + 128 + 28*2048*128 = 7.64M floats ~= 30.6 MB

__global__ __launch_bounds__(256) void k_tables(
    const float* __restrict__ w, const float* __restrict__ mu,
    const float* __restrict__ cov, float* __restrict__ ws) {
  int idx = blockIdx.x * 256 + threadIdx.x;   // grid covers KD exactly
  float* T  = ws;
  float* lw = ws + TBL;
  int d = idx >> 7;
  int k = idx & (NK - 1);
  float c = cov[k * ND + d];
  float m = mu[k * ND + d];
  float inv2 = 0.5f / c;
  T[d * 384 + k]       = -inv2;                           // ta
  T[d * 384 + 128 + k] = m / c;                           // tb
  T[d * 384 + 256 + k] = -m * m * inv2 - 0.5f * logf(c);  // tc
  if (idx < NK) lw[idx] = logf(w[idx]);
}

// Grid: (NB/BM) * DSPLIT = 32*28 = 896 blocks, 256 threads.
// tx = tid&31 -> k-quad (4 centers), ty = tid>>5 -> 8-row group.
// One LDS stage of 28 dims (43008 B), single barrier, 8-row register reuse.
__global__ __launch_bounds__(256, 3) void k_main(
    const float* __restrict__ data, const float* __restrict__ mask,
    const float* __restrict__ ws, float* __restrict__ part) {
  __shared__ float lds[DPB * 384];   // 10752 floats = 43008 B

  const float* T = ws;
  int mt  = blockIdx.x / DSPLIT;
  int dsp = blockIdx.x % DSPLIT;
  int r0  = mt * BM + (threadIdx.x >> 5) * 8;   // this thread's first row
  int d0  = dsp * DPB;
  int kb  = (threadIdx.x & 31) << 2;

  // stage the full table slice once: 28 dims * 384 floats = 2688 float4
  {
    const float4* src = (const float4*)(T + (size_t)d0 * 384);
    float4* dst = (float4*)lds;
    for (int i = threadIdx.x; i < DPB * 96; i += 256) dst[i] = src[i];
  }
  __syncthreads();

  float acc[8][4];
#pragma unroll
  for (int i = 0; i < 8; i++)
#pragma unroll
    for (int j = 0; j < 4; j++) acc[i][j] = 0.f;

#pragma unroll 1
  for (int dg = 0; dg < DPB; dg += 4) {
    float4 a[4], b[4], c[4];
#pragma unroll
    for (int dd = 0; dd < 4; dd++) {
      const float* base = lds + (dg + dd) * 384 + kb;
      a[dd] = *(const float4*)(base);
      b[dd] = *(const float4*)(base + 128);
      c[dd] = *(const float4*)(base + 256);
    }
#pragma unroll
    for (int rr = 0; rr < 8; rr++) {
      int r = r0 + rr;
      const float* dp = data + (size_t)r * ND + d0 + dg;
      const float* mp = mask + (size_t)r * ND + d0 + dg;
      float4 x = *(const float4*)dp;
      float4 m = *(const float4*)mp;
      float xs[4] = {x.x, x.y, x.z, x.w};
      float ms[4] = {m.x, m.y, m.z, m.w};
#pragma unroll
      for (int dd = 0; dd < 4; dd++) {
        float m0 = ms[dd];
        float m1 = m0 * xs[dd];
        float m2 = m1 * xs[dd];
        acc[rr][0] = fmaf(m2, a[dd].x, fmaf(m1, b[dd].x, fmaf(m0, c[dd].x, acc[rr][0])));
        acc[rr][1] = fmaf(m2, a[dd].y, fmaf(m1, b[dd].y, fmaf(m0, c[dd].y, acc[rr][1])));
        acc[rr][2] = fmaf(m2, a[dd].z, fmaf(m1, b[dd].z, fmaf(m0, c[dd].z, acc[rr][2])));
        acc[rr][3] = fmaf(m2, a[dd].w, fmaf(m1, b[dd].w, fmaf(m0, c[dd].w, acc[rr][3])));
      }
    }
  }

#pragma unroll
  for (int rr = 0; rr < 8; rr++) {
    int r = r0 + rr;
    float4 v = make_float4(acc[rr][0], acc[rr][1], acc[rr][2], acc[rr][3]);
    *(float4*)(part + ((size_t)dsp * NB + r) * NK + kb) = v;
  }
}

// One wave per batch row: lane handles k = {2*lane, 2*lane+1} (float2,
// fully coalesced). Reduce DSPLIT partials, +log w, NaN fix, LSE with the
// reference's per-term +1e-8, exp.
__global__ __launch_bounds__(256) void k_final(
    const float* __restrict__ ws, float* __restrict__ out) {
  const float* lw    = ws + TBL;
  const float2* part = (const float2*)(ws + TBL + NK);
  int lane = threadIdx.x & 63;
  int wv   = threadIdx.x >> 6;
  int b = blockIdx.x * 4 + wv;

  float2 s = make_float2(0.f, 0.f);
#pragma unroll
  for (int sp = 0; sp < DSPLIT; sp++) {
    float2 v = part[((size_t)sp * NB + b) * 64 + lane];
    s.x += v.x; s.y += v.y;
  }
  float2 l = ((const float2*)lw)[lane];
  s.x += l.x; s.y += l.y;
  if (isnan(s.x)) s.x = 0.f;
  if (isnan(s.y)) s.y = 0.f;

  float mx = fmaxf(s.x, s.y);
#pragma unroll
  for (int off = 32; off; off >>= 1) mx = fmaxf(mx, __shfl_xor(mx, off));
  // reference: sum_k (exp(dep-max) + 1e-8) -> 2 terms per lane
  float sum = expf(s.x - mx) + expf(s.y - mx) + 2e-8f;
#pragma unroll
  for (int off = 32; off; off >>= 1) sum += __shfl_xor(sum, off);
  float lse = logf(sum) + mx;
  float2 o = make_float2(expf(s.x - lse), expf(s.y - lse));
  ((float2*)out)[(size_t)b * 64 + lane] = o;
}

extern "C" void kernel_launch(void* const* d_in, const int* in_sizes, int n_in,
                              void* d_out, int out_size, void* d_ws, size_t ws_size,
                              hipStream_t stream) {
  const float* data = (const float*)d_in[0];
  const float* mask = (const float*)d_in[1];
  const float* wts  = (const float*)d_in[2];
  const float* mu   = (const float*)d_in[3];
  const float* cov  = (const float*)d_in[4];
  float* ws   = (float*)d_ws;
  float* part = ws + TBL + NK;
  float* out  = (float*)d_out;

  k_tables<<<KD / 256, 256, 0, stream>>>(wts, mu, cov, ws);
  k_main<<<(NB / BM) * DSPLIT, 256, 0, stream>>>(data, mask, ws, part);
  k_final<<<NB / 4, 256, 0, stream>>>(ws, out);
}